// Round 9
// baseline (339.926 us; speedup 1.0000x reference)
//
#include <hip/hip_runtime.h>
#include <stdint.h>

#define K_DIM 1024
#define B_SZ 4
#define N_SEQ 2048
#define HEADS 16
#define DH 64
#define M_TOT (B_SZ * N_SEQ)  // 8192

typedef __bf16 bf16x8 __attribute__((ext_vector_type(8)));
typedef __bf16 bf16x4 __attribute__((ext_vector_type(4)));
typedef __bf16 bf16x2 __attribute__((ext_vector_type(2)));
typedef float f32x4 __attribute__((ext_vector_type(4)));
typedef float f32x16 __attribute__((ext_vector_type(16)));

typedef const uint32_t __attribute__((address_space(1))) gas_u32;
typedef uint32_t __attribute__((address_space(3))) las_u32;

#define CE_SCALE 0.1803368801f  // 0.125 * log2(e), folded into Q projection

__device__ __forceinline__ uint16_t f2bf(float f) {
  uint32_t u = __float_as_uint(f);
  u += 0x7FFFu + ((u >> 16) & 1u);  // round-nearest-even
  return (uint16_t)(u >> 16);
}

__device__ __forceinline__ void gld_lds16(const uint16_t* g, uint16_t* lds) {
  __builtin_amdgcn_global_load_lds((gas_u32*)g, (las_u32*)lds, 16, 0, 0);
}

// pack two f32 -> one u32 of 2x bf16 (compiler emits v_cvt_pk_bf16_f32)
__device__ __forceinline__ uint32_t pkbf(float a, float b) {
  bf16x2 t;
  t[0] = (__bf16)a;
  t[1] = (__bf16)b;
  return __builtin_bit_cast(uint32_t, t);
}

// v_permlane32_swap_b32: a' = [a.lo | b.lo], b' = [a.hi | b.hi]
__device__ __forceinline__ void pswap(uint32_t& a, uint32_t& b) {
  asm("v_permlane32_swap_b32 %0, %1" : "+v"(a), "+v"(b));
}

// ---------------- fused preprocessing: activations fp32->bf16 + weight
// transpose-convert, ONE dispatch.
// blocks [0, 24576): convert Q/K/V activations (z = bid>>13, 8192 blocks each)
// blocks [24576, 28672): transpose Wq/Wk/Wv/Wo 32x32 tiles (1024 blocks each)
__global__ __launch_bounds__(256) void prep_k(const float* __restrict__ aq,
                                              const float* __restrict__ ak,
                                              const float* __restrict__ av,
                                              const float* __restrict__ w0,
                                              const float* __restrict__ w1,
                                              const float* __restrict__ w2,
                                              const float* __restrict__ w3,
                                              uint16_t* __restrict__ xdst,
                                              uint16_t* __restrict__ wdst) {
  __shared__ float tile[32][33];
  const int bid = blockIdx.x;
  const int tid = threadIdx.x;
  if (bid < 3 * 8192) {
    const int z = bid >> 13;
    const int xb = bid & 8191;
    const float* src = (z == 0) ? aq : (z == 1) ? ak : av;
    uint16_t* dst = xdst + (size_t)z * M_TOT * K_DIM;
    const int i = xb * 256 + tid;  // < 2097152 == NELEM/4 exactly
    float4 v = ((const float4*)src)[i];
    ushort4 o;
    o.x = f2bf(v.x); o.y = f2bf(v.y); o.z = f2bf(v.z); o.w = f2bf(v.w);
    ((ushort4*)dst)[i] = o;
  } else {
    const int t = bid - 3 * 8192;  // 0..4095
    const int z = t >> 10;
    const int rb = t & 1023;
    const float* src = (z == 0) ? w0 : (z == 1) ? w1 : (z == 2) ? w2 : w3;
    uint16_t* dst = wdst + (size_t)z * 1024 * 1024;
    const int tx = tid & 31, ty = tid >> 5;  // 32 x 8
    const int bx = (rb & 31) * 32, by = (rb >> 5) * 32;
#pragma unroll
    for (int i = 0; i < 32; i += 8)
      tile[ty + i][tx] = src[(size_t)(by + ty + i) * 1024 + bx + tx];
    __syncthreads();
#pragma unroll
    for (int i = 0; i < 32; i += 8)
      dst[(size_t)(bx + ty + i) * 1024 + by + tx] = f2bf(tile[tx][ty + i]);
  }
}

// ---------------- GEMM: C[M,1024] = A[M,1024] @ B[1024,1024], BT[n][k] given -----
// 128x128 tile, BK=32, 4 waves. v3 sync (T4, counted vmcnt): the r5 2-phase
// loop still drained vmcnt(0) at every __syncthreads -> prefetch never
// spanned the barrier (MfmaUtil 24%, ~670 TF; r8 bigger tile: neutral).
// Now: 4 LDS buffers (64KB), stage tile t+2 each iter, then inline-asm
// s_waitcnt vmcnt(8) (tiles t+1/t+2's 8 loads STAY in flight; only tile t's
// 4 must have landed) + raw s_barrier (no implicit drain), compute tile t.
// Hazard audit (4buf/1barrier): stage(t+2) writes buf[(t+2)&3], last read by
// compute(t-2); the issuing wave passed barrier(t-1), which all waves reached
// only after finishing compute(t-2) -> no overwrite race. Barrier after each
// wave's own vmcnt(8) => all waves' tile-t loads retired before any ds_read.
// Tail peeled with vmcnt(4)/vmcnt(0). sched_barrier(0) after asm waitcnt
// (guide rule 18). LDS chunk-XOR swizzle: 0 conflicts (r4-verified).
// MODE 3: fused QKV (z=0 Q scaled -> [B,H,N,Dh]; z=1 K; z=2 V -> [B,H,Dh,N])
// MODE 1: fp32 out row-major + bias (output projection), z=0 only.
template <int MODE>
__global__ __launch_bounds__(256, 2) void gemm_bf16(const uint16_t* __restrict__ A,
                                                    const uint16_t* __restrict__ BT,
                                                    void* __restrict__ Cout,
                                                    const float* __restrict__ bias) {
  __shared__ __align__(16) uint16_t As[4][128 * 32];  // 4 x 8KB
  __shared__ __align__(16) uint16_t Bs[4][128 * 32];  // 4 x 8KB
  const int tid = threadIdx.x;
  const int wave = tid >> 6, lane = tid & 63;
  const int g = lane >> 4, c16 = lane & 15;

  // swizzled block mapping
  const int bid = blockIdx.x;
  const int xcd = bid & 7;
  const int l = bid >> 3;
  const int z = (MODE == 3) ? (l >> 6) : 0;
  const int r = l & 63;
  const int n0 = (r & 7) * 128;
  const int m0 = (xcd * 8 + (r >> 3)) * 128;

  const int wr = wave >> 1, wc = wave & 1;
  float scale = 1.f;
  if (MODE == 3) {
    A += (size_t)z * M_TOT * K_DIM;
    BT += (size_t)z * 1024 * 1024;
    scale = (z == 0) ? CE_SCALE : 1.f;
  }

  const f32x4 fzero = {0.f, 0.f, 0.f, 0.f};
  f32x4 acc[4][4];
#pragma unroll
  for (int i = 0; i < 4; ++i)
#pragma unroll
    for (int j = 0; j < 4; ++j) acc[i][j] = fzero;

  const int srow = wave * 32 + (lane >> 2);
  // pre-swizzled source column: LDS slot (srow, lane&3) receives global chunk
  // (lane&3) ^ ((srow>>1)&3). Same key for srow+16.
  const int scol = (((lane & 3) ^ ((srow >> 1) & 3)) * 8);
  const uint16_t* ag0 = A + (size_t)(m0 + srow) * K_DIM + scol;
  const uint16_t* ag1 = A + (size_t)(m0 + srow + 16) * K_DIM + scol;
  const uint16_t* bg0 = BT + (size_t)(n0 + srow) * K_DIM + scol;
  const uint16_t* bg1 = BT + (size_t)(n0 + srow + 16) * K_DIM + scol;
  const int lofa0 = (wave * 32) * 32;
  const int lofa1 = (wave * 32 + 16) * 32;

  // read-side swizzle key: rows read are wr*64 + i*16 + c16 -> ((row>>1)&3)
  // == ((c16>>1)&3) for all i, wr.
  const int rk = (c16 >> 1) & 3;

#define STAGE_TILE(T)                                      \
  do {                                                     \
    const int sb_ = (T) & 3;                               \
    gld_lds16(ag0 + (T) * 32, &As[sb_][lofa0]);            \
    gld_lds16(ag1 + (T) * 32, &As[sb_][lofa1]);            \
    gld_lds16(bg0 + (T) * 32, &Bs[sb_][lofa0]);            \
    gld_lds16(bg1 + (T) * 32, &Bs[sb_][lofa1]);            \
  } while (0)

#define COMPUTE_TILE(T)                                                                   \
  do {                                                                                    \
    const int cb_ = (T) & 3;                                                              \
    bf16x8 avec[4], bvec[4];                                                              \
    _Pragma("unroll") for (int i = 0; i < 4; ++i) avec[i] =                               \
        *(const bf16x8*)&As[cb_][(wr * 64 + i * 16 + c16) * 32 + ((g ^ rk) << 3)];        \
    _Pragma("unroll") for (int j = 0; j < 4; ++j) bvec[j] =                               \
        *(const bf16x8*)&Bs[cb_][(wc * 64 + j * 16 + c16) * 32 + ((g ^ rk) << 3)];        \
    _Pragma("unroll") for (int i = 0; i < 4; ++i) _Pragma("unroll") for (int j = 0; j < 4;\
                                                                         ++j) acc[i][j] = \
        __builtin_amdgcn_mfma_f32_16x16x32_bf16(avec[i], bvec[j], acc[i][j], 0, 0, 0);    \
  } while (0)

  // prologue: stage tiles 0 and 1 (8 loads in flight)
  STAGE_TILE(0);
  STAGE_TILE(1);

  const int NT = K_DIM / 32;  // 32
  for (int t = 0; t < NT - 2; ++t) {
    STAGE_TILE(t + 2);  // 12 outstanding after issue
    asm volatile("s_waitcnt vmcnt(8)" ::: "memory");  // tile t landed; t+1,t+2 in flight
    __builtin_amdgcn_sched_barrier(0);
    __builtin_amdgcn_s_barrier();  // raw barrier: NO vmcnt(0) drain
    COMPUTE_TILE(t);
  }
  // tail: t = NT-2 (tile NT-1 still in flight), then t = NT-1
  asm volatile("s_waitcnt vmcnt(4)" ::: "memory");
  __builtin_amdgcn_sched_barrier(0);
  __builtin_amdgcn_s_barrier();
  COMPUTE_TILE(NT - 2);
  asm volatile("s_waitcnt vmcnt(0)" ::: "memory");
  __builtin_amdgcn_sched_barrier(0);
  __builtin_amdgcn_s_barrier();
  COMPUTE_TILE(NT - 1);

#undef STAGE_TILE
#undef COMPUTE_TILE

#pragma unroll
  for (int i = 0; i < 4; ++i) {
#pragma unroll
    for (int j = 0; j < 4; ++j) {
      const int col = n0 + wc * 64 + j * 16 + c16;
      if (MODE == 3 && z == 2) {
        const int h = col >> 6, d = col & 63;
        const int row0 = m0 + wr * 64 + i * 16 + g * 4;
        const int b = row0 >> 11, n = row0 & 2047;
        ushort4 o;
        o.x = f2bf(acc[i][j][0]); o.y = f2bf(acc[i][j][1]);
        o.z = f2bf(acc[i][j][2]); o.w = f2bf(acc[i][j][3]);
        *(ushort4*)&((uint16_t*)Cout)[(size_t)2 * M_TOT * 1024 +
                                      (((size_t)(b * HEADS + h)) * DH + d) * N_SEQ + n] = o;
      } else {
#pragma unroll
        for (int r2 = 0; r2 < 4; ++r2) {
          const int row = m0 + wr * 64 + i * 16 + g * 4 + r2;
          if (MODE == 3) {
            const int b = row >> 11, n = row & 2047;
            const int h = col >> 6, d = col & 63;
            ((uint16_t*)Cout)[(size_t)z * M_TOT * 1024 +
                              (((size_t)(b * HEADS + h)) * N_SEQ + n) * DH + d] =
                f2bf(acc[i][j][r2] * scale);
          } else {
            ((float*)Cout)[(size_t)row * 1024 + col] = acc[i][j][r2] + bias[col];
          }
        }
      }
    }
  }
}

// ---------------- flash attention v8 ----------------
// 256 threads (4 waves), 64 q/wave (2 sub-tiles of 32), 64-key tiles, double-
// buffered XOR-swizzled LDS, reg-staged prefetch.
// QK^T via mfma_f32_32x32x16_bf16 (A=K, B=Q): lane holds S^T[key=(r&3)+8(r>>2)+4hi]
// [query=lane&31]. exp2 in f32 regs, pack via cvt_pk_bf16 + v_permlane32_swap
// directly into the 32x32x16 A-fragment layout (k = hi*8+j) -> PV at full K=16
// per instr, 4096 FLOP/cy rate.
__global__ __launch_bounds__(256, 2) void attention_k(const uint16_t* __restrict__ qm,
                                                      const uint16_t* __restrict__ km,
                                                      const uint16_t* __restrict__ vtm,
                                                      uint16_t* __restrict__ om) {
  __shared__ __align__(16) uint16_t Ks[2 * 64 * 64];
  __shared__ __align__(16) uint16_t Vs[2 * 64 * 64];
  const int tid = threadIdx.x;
  const int wave = tid >> 6, lane = tid & 63;
  const int lrow = lane & 31;  // key_local (QK-A) / query (QK-B) / d_local (PV-B)
  const int hi = lane >> 5;

  const int bid = blockIdx.x;
  const int xcd = bid & 7;
  const int l0 = bid >> 3;
  const int bh = xcd * 8 + (l0 & 7);
  const int qblk = l0 >> 3;
  const int b = bh >> 4, h = bh & 15;
  const int q0w = qblk * 256 + wave * 64;

  const uint16_t* qbase = qm + (size_t)bh * N_SEQ * DH;
  const uint16_t* kbase = km + (size_t)bh * N_SEQ * DH;
  const uint16_t* vbase = vtm + (size_t)bh * DH * N_SEQ;

  // Q as 32x32x16 B-fragments: n = query = lrow, k(d) = step*16 + hi*8 + j
  bf16x8 qf[2][4];
#pragma unroll
  for (int qs = 0; qs < 2; ++qs) {
    const uint16_t* qp = qbase + (size_t)(q0w + qs * 32 + lrow) * DH + hi * 8;
#pragma unroll
    for (int step = 0; step < 4; ++step) qf[qs][step] = *(const bf16x8*)(qp + step * 16);
  }

  // loop-invariant swizzled LDS element offsets
  int koff[2][4];  // [ks][step]: K A-frag, row = ks*32+lrow, d = step*16+hi*8
  int voff[2][2][2];  // [ks][s][dt]: V B-frag, row(d) = dt*32+lrow, key = ks*32+s*16+hi*8
#pragma unroll
  for (int ks = 0; ks < 2; ++ks) {
    const int krow = ks * 32 + lrow;
#pragma unroll
    for (int step = 0; step < 4; ++step)
      koff[ks][step] = krow * 64 + ((((step << 1) | hi) ^ (krow & 7)) << 3);
#pragma unroll
    for (int s = 0; s < 2; ++s)
#pragma unroll
      for (int dt = 0; dt < 2; ++dt)
        voff[ks][s][dt] =
            (dt * 32 + lrow) * 64 + ((((ks << 2) | (s << 1) | hi) ^ (lrow & 7)) << 3);
  }

  f32x16 oacc[2][2];  // [qs][dt]: col = d_local = lrow, row(query) = (r&3)+8(r>>2)+4hi
#pragma unroll
  for (int qs = 0; qs < 2; ++qs)
#pragma unroll
    for (int dt = 0; dt < 2; ++dt)
#pragma unroll
      for (int i = 0; i < 16; ++i) oacc[qs][dt][i] = 0.f;
  float l[2] = {0.f, 0.f};

  // staging: 256 threads, 2 chunks each per tensor (row = key for K, d for V^T)
  const int ch = tid & 7;
  const int krow0 = tid >> 3, krow1 = 32 + (tid >> 3);
  const int kdst0 = krow0 * 64 + ((ch ^ (krow0 & 7)) << 3);
  const int kdst1 = krow1 * 64 + ((ch ^ (krow1 & 7)) << 3);

  uint4 kp0, kp1, vp0, vp1;
  kp0 = *(const uint4*)&kbase[(size_t)tid * 8];
  kp1 = *(const uint4*)&kbase[(size_t)(256 + tid) * 8];
  vp0 = *(const uint4*)&vbase[(size_t)krow0 * N_SEQ + ch * 8];
  vp1 = *(const uint4*)&vbase[(size_t)krow1 * N_SEQ + ch * 8];
  *(uint4*)&Ks[kdst0] = kp0;
  *(uint4*)&Ks[kdst1] = kp1;
  *(uint4*)&Vs[kdst0] = vp0;
  *(uint4*)&Vs[kdst1] = vp1;
  __syncthreads();

  for (int t = 0; t < N_SEQ / 64; ++t) {
    const int cur = t & 1;
    if (t < N_SEQ / 64 - 1) {
      const size_t ko = (size_t)(t + 1) * 4096;
      const int vc = (t + 1) * 64;
      kp0 = *(const uint4*)&kbase[ko + (size_t)tid * 8];
      kp1 = *(const uint4*)&kbase[ko + (size_t)(256 + tid) * 8];
      vp0 = *(const uint4*)&vbase[(size_t)krow0 * N_SEQ + vc + ch * 8];
      vp1 = *(const uint4*)&vbase[(size_t)krow1 * N_SEQ + vc + ch * 8];
    }
    const uint16_t* ksp = &Ks[cur * 4096];
    const uint16_t* vsp = &Vs[cur * 4096];

#pragma unroll
    for (int ks = 0; ks < 2; ++ks) {
      bf16x8 kf[4];
#pragma unroll
      for (int step = 0; step < 4; ++step) kf[step] = *(const bf16x8*)&ksp[koff[ks][step]];

      f32x16 z[2];
#pragma unroll
      for (int qs = 0; qs < 2; ++qs)
#pragma unroll
        for (int i = 0; i < 16; ++i) z[qs][i] = 0.f;

      __builtin_amdgcn_s_setprio(1);
#pragma unroll
      for (int step = 0; step < 4; ++step)
        z[0] = __builtin_amdgcn_mfma_f32_32x32x16_bf16(kf[step], qf[0][step], z[0], 0, 0, 0);
#pragma unroll
      for (int step = 0; step < 4; ++step)
        z[1] = __builtin_amdgcn_mfma_f32_32x32x16_bf16(kf[step], qf[1][step], z[1], 0, 0, 0);
      __builtin_amdgcn_s_setprio(0);

      // softmax piece + pack into PV A-fragments (keys hi*8+j per lane)
      uint32_t pa[2][2][4];  // [qs][s][word]
#pragma unroll
      for (int qs = 0; qs < 2; ++qs) {
        float p[16];
#pragma unroll
        for (int r = 0; r < 16; ++r) p[r] = __builtin_amdgcn_exp2f(z[qs][r]);
        l[qs] += (((p[0] + p[1]) + (p[2] + p[3])) + ((p[4] + p[5]) + (p[6] + p[7]))) +
                 (((p[8] + p[9]) + (p[10] + p[11])) + ((p[12] + p[13]) + (p[14] + p[15])));
#pragma unroll
        for (int s = 0; s < 2; ++s) {
          uint32_t w0 = pkbf(p[s * 8 + 0], p[s * 8 + 1]);
          uint32_t w1 = pkbf(p[s * 8 + 2], p[s * 8 + 3]);
          uint32_t w2 = pkbf(p[s * 8 + 4], p[s * 8 + 5]);
          uint32_t w3 = pkbf(p[s * 8 + 6], p[s * 8 + 7]);
          pswap(w0, w2);  // -> frag words 0 and 2
          pswap(w1, w3);  // -> frag words 1 and 3
          pa[qs][s][0] = w0; pa[qs][s][1] = w1; pa[qs][s][2] = w2; pa[qs][s][3] = w3;
        }
      }

      bf16x8 vf[2][2];
#pragma unroll
      for (int s = 0; s < 2; ++s)
#pragma unroll
        for (int dt = 0; dt < 2; ++dt) vf[s][dt] = *(const bf16x8*)&vsp[voff[ks][s][dt]];

      __builtin_amdgcn_s_setprio(1);
#pragma unroll
      for (int s = 0; s < 2; ++s)
#pragma unroll
        for (int qs = 0; qs < 2; ++qs) {
          uint4 u;
          u.x = pa[qs][s][0]; u.y = pa[qs][s][1]; u.z = pa[qs][s][2]; u.w = pa[qs][s][3];
          const bf16x8 paf = __builtin_bit_cast(bf16x8, u);
          oacc[qs][0] = __builtin_amdgcn_mfma_f32_32x32x16_bf16(paf, vf[s][0], oacc[qs][0], 0, 0, 0);
          oacc[qs][1] = __builtin_amdgcn_mfma_f32_32x32x16_bf16(paf, vf[s][1], oacc[qs][1], 0, 0, 0);
        }
      __builtin_amdgcn_s_setprio(0);
    }

    if (t < N_SEQ / 64 - 1) {
      // write NEXT tile into the other buffer; its previous readers finished
      // before the barrier at the end of iteration t-1.
      *(uint4*)&Ks[(cur ^ 1) * 4096 + kdst0] = kp0;
      *(uint4*)&Ks[(cur ^ 1) * 4096 + kdst1] = kp1;
      *(uint4*)&Vs[(cur ^ 1) * 4096 + kdst0] = vp0;
      *(uint4*)&Vs[(cur ^ 1) * 4096 + kdst1] = vp1;
      __syncthreads();
    }
  }

  // finalize denominators: lane's l is partial over its hi-half's key set
#pragma unroll
  for (int qs = 0; qs < 2; ++qs) l[qs] += __shfl_xor(l[qs], 32);

#pragma unroll
  for (int qs = 0; qs < 2; ++qs) {
#pragma unroll
    for (int r = 0; r < 16; ++r) {
      const int ql = (r & 3) + 8 * (r >> 2) + 4 * hi;  // query_local of this reg
      const float lr = __shfl(l[qs], ql);
      const float inv = 1.f / lr;
      const int row = q0w + qs * 32 + ql;
      const size_t base = ((size_t)b * N_SEQ + row) * 1024 + h * 64;
      om[base + lrow] = f2bf(oacc[qs][0][r] * inv);
      om[base + 32 + lrow] = f2bf(oacc[qs][1][r] * inv);
    }
  }
}

// ---------------- LayerNorm + residual ----------------
__global__ __launch_bounds__(256) void ln_res_k(const float* __restrict__ proj,
                                                const float* __restrict__ query,
                                                const float* __restrict__ gamma,
                                                const float* __restrict__ beta,
                                                float* __restrict__ out) {
  const int row = blockIdx.x;
  const int tid = threadIdx.x;
  const size_t base = (size_t)row * 1024 + tid * 4;
  float4 v = *(const float4*)(proj + base);
  float s = v.x + v.y + v.z + v.w;
  float s2 = v.x * v.x + v.y * v.y + v.z * v.z + v.w * v.w;
#pragma unroll
  for (int off = 1; off < 64; off <<= 1) {
    s += __shfl_xor(s, off);
    s2 += __shfl_xor(s2, off);
  }
  __shared__ float red[8];
  const int wave = tid >> 6, lane = tid & 63;
  if (lane == 0) { red[wave] = s; red[4 + wave] = s2; }
  __syncthreads();
  s = red[0] + red[1] + red[2] + red[3];
  s2 = red[4] + red[5] + red[6] + red[7];
  const float mu = s * (1.f / 1024.f);
  const float var = fmaxf(s2 * (1.f / 1024.f) - mu * mu, 0.f);
  const float rstd = rsqrtf(var + 1e-5f);
  float4 gq = *(const float4*)(gamma + tid * 4);
  float4 bq = *(const float4*)(beta + tid * 4);
  float4 qq = *(const float4*)(query + base);
  float4 o;
  o.x = (v.x - mu) * rstd * gq.x + bq.x + qq.x;
  o.y = (v.y - mu) * rstd * gq.y + bq.y + qq.y;
  o.z = (v.z - mu) * rstd * gq.z + bq.z + qq.z;
  o.w = (v.w - mu) * rstd * gq.w + bq.w + qq.w;
  *(float4*)(out + base) = o;
}

extern "C" void kernel_launch(void* const* d_in, const int* in_sizes, int n_in,
                              void* d_out, int out_size, void* d_ws, size_t ws_size,
                              hipStream_t stream) {
  (void)in_sizes; (void)n_in; (void)out_size; (void)ws_size;
  const float* query = (const float*)d_in[0];
  const float* key_ = (const float*)d_in[1];
  const float* value = (const float*)d_in[2];
  const float* Wq = (const float*)d_in[3];
  const float* Wk = (const float*)d_in[4];
  const float* Wv = (const float*)d_in[5];
  const float* Wo = (const float*)d_in[6];
  const float* bo = (const float*)d_in[7];
  const float* gamma = (const float*)d_in[8];
  const float* beta = (const float*)d_in[9];
  float* out = (float*)d_out;

  const size_t NELEM = (size_t)M_TOT * 1024;  // 8388608
  uint16_t* wsp = (uint16_t*)d_ws;
  uint16_t* WqT = wsp;                   // 4 x 1M bf16 (Wq,Wk,Wv,Wo contiguous)
  uint16_t* WoT = WqT + 3 * 1024 * 1024;
  uint16_t* xq = WqT + 4 * 1024 * 1024;  // xq,xk,xv contiguous (3 x NELEM)
  uint16_t* qb = xq + 3 * NELEM;         // qb,kb,vt contiguous (z * NELEM)
  uint16_t* attnO = xq;                  // alias: xq dead after QKV-GEMM
  float* proj = (float*)(xq + NELEM);    // alias: xk+xv dead after QKV-GEMM (32MB)

  // fused preprocessing: 24576 conv blocks + 4096 transpose blocks
  prep_k<<<28672, 256, 0, stream>>>(query, key_, value, Wq, Wk, Wv, Wo, xq, WqT);

  gemm_bf16<3><<<1536, 256, 0, stream>>>(xq, WqT, qb, nullptr);

  attention_k<<<512, 256, 0, stream>>>(qb, qb + NELEM, qb + 2 * NELEM, attnO);

  gemm_bf16<1><<<512, 256, 0, stream>>>(attnO, WoT, proj, bo);

  ln_res_k<<<8192, 256, 0, stream>>>(proj, query, gamma, beta, out);
}